// Round 9
// baseline (24056.323 us; speedup 1.0000x reference)
//
#include <hip/hip_runtime.h>
#include <math.h>

// MPNN on MI355X. R9: GRU rebuilt around the empirical rule found in R8:
// scalar-weight GEMV passes are fast iff the per-pass weight working set
// fits the 16KB scalar cache (edge/node_pre obey it; R8's GRU used 48KB
// chunks -> s_load thrash, 0.58GB scalar fetch, 1ms/dispatch). Now:
// gate-sequential passes over 32-col j-chunks (128k x 32j x 4B = 16KB),
// 4 threads per node (one chunk each) -> 2000 blocks for latency hiding.

#define DDIM 128
#define NTOT 128000
#define HBYTES 65536000ULL   // 128000*128*4
#define EBLK 128

__device__ __forceinline__ float gelu_exact(float x) {
    return 0.5f * x * (1.0f + erff(x * 0.70710678118654752440f));
}
__device__ __forceinline__ float sigmoidf_(float x) {
    return 1.0f / (1.0f + expf(-x));
}

__global__ __launch_bounds__(256) void embed_kernel(
    const int* __restrict__ inp, const float* __restrict__ table,
    float* __restrict__ h)
{
    int gid = blockIdx.x * 256 + threadIdx.x;
    if (gid >= NTOT * 32) return;
    int row = gid >> 5;
    int q   = gid & 31;
    int b   = row / 4000;
    int n   = (row % 4000) % 1000;
    int e   = inp[b * 1000 + n];
    ((float4*)h)[gid] = ((const float4*)table)[e * 32 + q];
}

__global__ __launch_bounds__(256) void hist_kernel(
    const int* __restrict__ ni, const int* __restrict__ bi, int E,
    int* __restrict__ deg)
{
    int g = blockIdx.x * 256 + threadIdx.x;
    if (g < E)          atomicAdd(&deg[bi[g]], 1);
    else if (g < 2 * E) atomicAdd(&deg[ni[g - E]], 1);
}

__global__ __launch_bounds__(256) void blockscan_kernel(
    const int* __restrict__ deg, int* __restrict__ offp, int* __restrict__ bsum)
{
    __shared__ int s[256];
    int tid = threadIdx.x;
    int i = blockIdx.x * 256 + tid;
    int v = deg[i];
    s[tid] = v;
    __syncthreads();
    for (int off = 1; off < 256; off <<= 1) {
        int t = (tid >= off) ? s[tid - off] : 0;
        __syncthreads();
        s[tid] += t;
        __syncthreads();
    }
    offp[i] = s[tid] - v;
    if (tid == 255) bsum[blockIdx.x] = s[255];
}

__global__ __launch_bounds__(512) void bscan_kernel(
    const int* __restrict__ bsum, int* __restrict__ bexc, int nb)
{
    __shared__ int s[512];
    int t = threadIdx.x;
    int v = (t < nb) ? bsum[t] : 0;
    s[t] = v;
    __syncthreads();
    for (int off = 1; off < 512; off <<= 1) {
        int u = (t >= off) ? s[t - off] : 0;
        __syncthreads();
        s[t] += u;
        __syncthreads();
    }
    if (t < nb) bexc[t] = s[t] - v;
}

__global__ __launch_bounds__(256) void fill_kernel(
    const int* __restrict__ ni, const int* __restrict__ bi, int E,
    const int* __restrict__ offp, const int* __restrict__ bexc,
    int* __restrict__ cursor, int* __restrict__ elist, int* __restrict__ slotseg)
{
    int g = blockIdx.x * 256 + threadIdx.x;
    if (g >= 2 * E) return;
    int seg = (g < E) ? bi[g] : ni[g - E];
    int pos = atomicAdd(&cursor[seg], 1);
    int slot = offp[seg] + bexc[seg >> 8] + pos;
    elist[slot] = g;
    slotseg[slot] = seg;
}

// Per-node stage-1 factorization: p[v][0:64) = Wtop@h[v] + bin,
// p[v][64:128) = Wbot@h[v]. 16KB weight working set per pass.
__global__ __launch_bounds__(256) void node_pre_kernel(
    const float* __restrict__ h, const float* __restrict__ Win,
    const float* __restrict__ bin, float* __restrict__ p)
{
    const int node = blockIdx.x * 256 + threadIdx.x;
    const float4* h4 = (const float4*)(h + (size_t)node * DDIM);
    float* prow = p + (size_t)node * DDIM;

    for (int c = 0; c < 4; ++c) {
        const int top   = (c < 2) ? 1 : 0;
        const int j0    = (c & 1) * 32;
        const int kbase = top ? 0 : 128;
        float acc[32];
        #pragma unroll
        for (int j = 0; j < 32; ++j) acc[j] = top ? bin[j0 + j] : 0.0f;
        for (int k4 = 0; k4 < 32; ++k4) {
            float4 hv = h4[k4];
            #pragma unroll
            for (int kk = 0; kk < 4; ++kk) {
                const float hk = (&hv.x)[kk];
                const float* wr = Win + (size_t)(kbase + k4 * 4 + kk) * 64 + j0;
                #pragma unroll
                for (int j = 0; j < 32; ++j) acc[j] = fmaf(hk, wr[j], acc[j]);
            }
        }
        float* dst = prow + (top ? 0 : 64) + j0;
        #pragma unroll
        for (int q = 0; q < 8; ++q)
            ((float4*)dst)[q] = make_float4(acc[q*4], acc[q*4+1],
                                            acc[q*4+2], acc[q*4+3]);
    }
}

// Edge MLP from precomputed p, CSR-sorted slots + fused segmented reduction.
__global__ __launch_bounds__(EBLK) void edge_mlp_kernel3(
    const int* __restrict__ ni, const int* __restrict__ bi, int E,
    const int* __restrict__ elist, const int* __restrict__ slotseg,
    const float* __restrict__ p,
    const float* __restrict__ Whid, const float* __restrict__ bhid,
    const float* __restrict__ Wout, const float* __restrict__ bout,
    float* __restrict__ sbuf)
{
    __shared__ float xs[EBLK * 65];
    __shared__ float scat[16 * 68];
    __shared__ int   segLDS[EBLK];
    __shared__ int   segedge[2];
    const int tid  = threadIdx.x;
    const int lane = tid & 63;
    const int s0   = blockIdx.x * EBLK;
    const int slot = s0 + tid;

    const int seg = slotseg[slot];
    const int g   = (seg >= 0) ? elist[slot] : 0;
    int first = 0, second = 0;
    if (seg >= 0) {
        if (g < E) { first = ni[g];     second = bi[g];     }
        else       { first = bi[g - E]; second = ni[g - E]; }
    }
    segLDS[tid] = seg;
    if (tid == 0) segedge[0] = slotseg[s0 - 1];
    if (tid == 1) segedge[1] = slotseg[s0 + EBLK];

    {
        const float4* pa = (const float4*)(p + (size_t)first  * DDIM);
        const float4* pb = (const float4*)(p + (size_t)second * DDIM + 64);
        #pragma unroll 4
        for (int q = 0; q < 16; ++q) {
            float4 a = pa[q], b = pb[q];
            xs[tid * 65 + q * 4 + 0] = gelu_exact(a.x + b.x);
            xs[tid * 65 + q * 4 + 1] = gelu_exact(a.y + b.y);
            xs[tid * 65 + q * 4 + 2] = gelu_exact(a.z + b.z);
            xs[tid * 65 + q * 4 + 3] = gelu_exact(a.w + b.w);
        }
    }

    for (int L = 0; L < 3; ++L) {
        float acc[64];
        #pragma unroll
        for (int j = 0; j < 64; ++j) acc[j] = bhid[L * 64 + j];
        #pragma unroll 4
        for (int k = 0; k < 64; ++k) {
            const float xk = xs[tid * 65 + k];
            const float* wr = Whid + (size_t)L * 4096 + (size_t)k * 64;
            #pragma unroll
            for (int j = 0; j < 64; ++j) acc[j] = fmaf(xk, wr[j], acc[j]);
        }
        #pragma unroll
        for (int j = 0; j < 64; ++j) xs[tid * 65 + j] = gelu_exact(acc[j]);
    }

    for (int half = 0; half < 2; ++half) {
        float acc[64];
        #pragma unroll
        for (int j = 0; j < 64; ++j) acc[j] = bout[half * 64 + j];
        #pragma unroll 4
        for (int k = 0; k < 64; ++k) {
            const float xk = xs[tid * 65 + k];
            const float* wr = Wout + (size_t)k * 128 + half * 64;
            #pragma unroll
            for (int j = 0; j < 64; ++j) acc[j] = fmaf(xk, wr[j], acc[j]);
        }

        int   runSeg = -2;
        float runacc = 0.0f;
        bool  leftC  = true;
        for (int b = 0; b < 8; ++b) {
            __syncthreads();
            if ((tid >> 4) == b) {
                float4* dp = (float4*)&scat[(tid & 15) * 68];
                #pragma unroll
                for (int q = 0; q < 16; ++q)
                    dp[q] = make_float4(acc[q*4], acc[q*4+1], acc[q*4+2], acc[q*4+3]);
            }
            __syncthreads();
            if (tid < 64) {
                for (int r = 0; r < 16; ++r) {
                    const int rowi = b * 16 + r;
                    const int sg = segLDS[rowi];
                    const float v = scat[r * 68 + lane];
                    if (sg != runSeg) {
                        if (runSeg >= 0) {
                            float* pp = sbuf + (size_t)runSeg * DDIM + half * 64 + lane;
                            if (leftC) *pp = runacc;
                            else       atomicAdd(pp, runacc);
                        }
                        runSeg = sg;
                        runacc = v;
                        leftC  = (rowi == 0) ? (segedge[0] != sg) : true;
                    } else {
                        runacc += v;
                    }
                }
            }
        }
        if (tid < 64 && runSeg >= 0) {
            const bool rightC = (segedge[1] != runSeg);
            float* pp = sbuf + (size_t)runSeg * DDIM + half * 64 + lane;
            if (leftC && rightC) *pp = runacc;
            else                 atomicAdd(pp, runacc);
        }
        __syncthreads();
    }
}

// GRU pass: ACC[32] += (row * SCALE) @ W[:, CB..CB+32); W row stride 384.
// Weight working set per pass: 128 rows x 128B = 16KB -> scalar-cache hot.
#define GPASS(ACC, R4, W, CB, SCALE)                                           \
    _Pragma("unroll 2")                                                        \
    for (int k4 = 0; k4 < 32; ++k4) {                                          \
        float4 v_ = (R4)[k4];                                                  \
        _Pragma("unroll")                                                      \
        for (int kk = 0; kk < 4; ++kk) {                                       \
            const float xk_ = (&v_.x)[kk] * (SCALE);                           \
            const float* wr_ = (W) + (size_t)(k4 * 4 + kk) * 384 + (CB);       \
            _Pragma("unroll")                                                  \
            for (int j = 0; j < 32; ++j) ACC[j] = fmaf(xk_, wr_[j], ACC[j]);   \
        }                                                                      \
    }

// GRU (keras reset_after): 4 threads per node, each owns one 32-col chunk.
// Gate-sequential (r -> hh -> cand -> z); <=64 acc floats live.
__global__ __launch_bounds__(256) void gru_kernel4(
    const float* __restrict__ h, const float* __restrict__ msum,
    const int* __restrict__ deg,
    const float* __restrict__ Wx, const float* __restrict__ Wh,
    const float* __restrict__ bi, const float* __restrict__ br,
    float* __restrict__ hout)
{
    const int gid  = blockIdx.x * 256 + threadIdx.x;   // 512000 threads
    const int node = gid >> 2;
    const int ch   = gid & 3;
    const int j0   = ch * 32;
    const int dg   = deg[node];
    const float cinv = (dg > 0) ? (1.0f / (float)dg) : 0.0f;
    const float4* m4 = (const float4*)(msum + (size_t)node * DDIM);
    const float4* h4 = (const float4*)(h    + (size_t)node * DDIM);
    float* orow = hout + (size_t)node * DDIM;

    // r_pre
    float rv[32];
    #pragma unroll
    for (int j = 0; j < 32; ++j) rv[j] = bi[128 + j0 + j] + br[128 + j0 + j];
    GPASS(rv, m4, Wx, 128 + j0, cinv)
    GPASS(rv, h4, Wh, 128 + j0, 1.0f)
    // hh
    float hh[32];
    #pragma unroll
    for (int j = 0; j < 32; ++j) hh[j] = br[256 + j0 + j];
    GPASS(hh, h4, Wh, 256 + j0, 1.0f)
    // cand = tanh(xh + sigmoid(r)*hh)
    #pragma unroll
    for (int j = 0; j < 32; ++j)
        rv[j] = sigmoidf_(rv[j]) * hh[j] + bi[256 + j0 + j];
    GPASS(rv, m4, Wx, 256 + j0, cinv)
    #pragma unroll
    for (int j = 0; j < 32; ++j) rv[j] = tanhf(rv[j]);
    // z_pre
    #pragma unroll
    for (int j = 0; j < 32; ++j) hh[j] = bi[j0 + j] + br[j0 + j];
    GPASS(hh, m4, Wx, j0, cinv)
    GPASS(hh, h4, Wh, j0, 1.0f)
    // blend + write this chunk
    #pragma unroll
    for (int q = 0; q < 8; ++q) {
        float4 hc = h4[ch * 8 + q];
        float4 o;
        #pragma unroll
        for (int kk = 0; kk < 4; ++kk) {
            int j = q * 4 + kk;
            float z = sigmoidf_(hh[j]);
            (&o.x)[kk] = z * (&hc.x)[kk] + (1.0f - z) * rv[j];
        }
        ((float4*)orow)[ch * 8 + q] = o;
    }
}

// Readout: block=64, activations in LDS slice, weights direct from global.
__global__ __launch_bounds__(64) void readout_kernel(
    const float* __restrict__ h,
    const float* __restrict__ Win,  const float* __restrict__ bin,
    const float* __restrict__ Whid, const float* __restrict__ bhid,
    const float* __restrict__ Wout, const float* __restrict__ bout,
    float* __restrict__ out)
{
    __shared__ float xs[64 * 65];
    const int tid = threadIdx.x;
    const int row = blockIdx.x * 64 + tid;
    const int b = row / 1000, n = row % 1000;
    const float4* xrow = (const float4*)(h + ((size_t)b * 4000 + n) * DDIM);

    {
        float acc[64];
        #pragma unroll
        for (int j = 0; j < 64; ++j) acc[j] = bin[j];
        #pragma unroll 2
        for (int k4 = 0; k4 < 32; ++k4) {
            float4 xv = xrow[k4];
            #pragma unroll
            for (int kk = 0; kk < 4; ++kk) {
                const float xk = (&xv.x)[kk];
                const float* wr = Win + (size_t)(k4 * 4 + kk) * 64;
                #pragma unroll
                for (int j = 0; j < 64; ++j) acc[j] = fmaf(xk, wr[j], acc[j]);
            }
        }
        #pragma unroll
        for (int j = 0; j < 64; ++j) xs[tid * 65 + j] = gelu_exact(acc[j]);
    }

    for (int L = 0; L < 3; ++L) {
        float acc[64];
        #pragma unroll
        for (int j = 0; j < 64; ++j) acc[j] = bhid[L * 64 + j];
        #pragma unroll 4
        for (int k = 0; k < 64; ++k) {
            const float xk = xs[tid * 65 + k];
            const float* wr = Whid + (size_t)L * 4096 + (size_t)k * 64;
            #pragma unroll
            for (int j = 0; j < 64; ++j) acc[j] = fmaf(xk, wr[j], acc[j]);
        }
        #pragma unroll
        for (int j = 0; j < 64; ++j) xs[tid * 65 + j] = gelu_exact(acc[j]);
    }

    float acc[10];
    #pragma unroll
    for (int pj = 0; pj < 10; ++pj) acc[pj] = bout[pj];
    #pragma unroll 4
    for (int k = 0; k < 64; ++k) {
        const float xk = xs[tid * 65 + k];
        const float* wr = Wout + k * 10;
        #pragma unroll
        for (int pj = 0; pj < 10; ++pj) acc[pj] = fmaf(xk, wr[pj], acc[pj]);
    }
    #pragma unroll
    for (int pj = 0; pj < 10; ++pj) out[(size_t)row * 10 + pj] = acc[pj];
}

extern "C" void kernel_launch(void* const* d_in, const int* in_sizes, int n_in,
                              void* d_out, int out_size, void* d_ws, size_t ws_size,
                              hipStream_t stream) {
    const int*   node_inputs = (const int*)d_in[0];
    const int*   ni_int = (const int*)d_in[1];
    const int*   bi_int = (const int*)d_in[2];
    const int*   ni_tmp = (const int*)d_in[3];
    const int*   bi_tmp = (const int*)d_in[4];
    const float* embed  = (const float*)d_in[5];
    const float* mWin   = (const float*)d_in[6];
    const float* mbin   = (const float*)d_in[7];
    const float* mWhid  = (const float*)d_in[8];
    const float* mbhid  = (const float*)d_in[9];
    const float* mWout  = (const float*)d_in[10];
    const float* mbout  = (const float*)d_in[11];
    const float* roWin  = (const float*)d_in[12];
    const float* robin  = (const float*)d_in[13];
    const float* roWhid = (const float*)d_in[14];
    const float* robhid = (const float*)d_in[15];
    const float* roWout = (const float*)d_in[16];
    const float* robout = (const float*)d_in[17];
    const float* giWx = (const float*)d_in[18];
    const float* giWh = (const float*)d_in[19];
    const float* gibi = (const float*)d_in[20];
    const float* gibr = (const float*)d_in[21];
    const float* gtWx = (const float*)d_in[22];
    const float* gtWh = (const float*)d_in[23];
    const float* gtbi = (const float*)d_in[24];
    const float* gtbr = (const float*)d_in[25];
    float* out = (float*)d_out;

    const int E_INT = 200000, E_TMP = 96000;
    const int NSLOT_I = 400000;   // 3125*128 exact
    const int NSLOT_T = 192000;   // 1500*128 exact

    char* ws = (char*)d_ws;
    float* A  = (float*)(ws);                 // h
    float* Bs = (float*)(ws + HBYTES);        // segment sums
    float* C  = (float*)(ws + 2 * HBYTES);    // scratch: p, then h'
    char*  ib = ws + 3 * HBYTES;

    int* deg_i   = (int*)(ib);
    int* deg_t   = (int*)(ib + 512000);
    int* offp_i  = (int*)(ib + 1024000);
    int* offp_t  = (int*)(ib + 1536000);
    int* bexc_i  = (int*)(ib + 2048000);
    int* bexc_t  = (int*)(ib + 2052096);
    int* bsum    = (int*)(ib + 2056192);
    int* cursor  = (int*)(ib + 2060288);
    int* el_i    = (int*)(ib + 2572288);
    int* el_t    = (int*)(ib + 4172288);
    int* ssi_raw = (int*)(ib + 4940288);
    int* sst_raw = (int*)(ib + 6540296);
    int* ssi = ssi_raw + 1;
    int* sst = sst_raw + 1;

    embed_kernel<<<16000, 256, 0, stream>>>(node_inputs, embed, A);

    hipMemsetAsync(deg_i, 0, NTOT * sizeof(int), stream);
    hipMemsetAsync(deg_t, 0, NTOT * sizeof(int), stream);
    hist_kernel<<<(2 * E_INT + 255) / 256, 256, 0, stream>>>(ni_int, bi_int, E_INT, deg_i);
    hist_kernel<<<(2 * E_TMP + 255) / 256, 256, 0, stream>>>(ni_tmp, bi_tmp, E_TMP, deg_t);

    hipMemsetAsync(ssi_raw, 0xFF, (size_t)(NSLOT_I + 2) * sizeof(int), stream);
    hipMemsetAsync(sst_raw, 0xFF, (size_t)(NSLOT_T + 2) * sizeof(int), stream);

    blockscan_kernel<<<500, 256, 0, stream>>>(deg_i, offp_i, bsum);
    bscan_kernel<<<1, 512, 0, stream>>>(bsum, bexc_i, 500);
    hipMemsetAsync(cursor, 0, NTOT * sizeof(int), stream);
    fill_kernel<<<(2 * E_INT + 255) / 256, 256, 0, stream>>>(
        ni_int, bi_int, E_INT, offp_i, bexc_i, cursor, el_i, ssi);

    blockscan_kernel<<<500, 256, 0, stream>>>(deg_t, offp_t, bsum);
    bscan_kernel<<<1, 512, 0, stream>>>(bsum, bexc_t, 500);
    hipMemsetAsync(cursor, 0, NTOT * sizeof(int), stream);
    fill_kernel<<<(2 * E_TMP + 255) / 256, 256, 0, stream>>>(
        ni_tmp, bi_tmp, E_TMP, offp_t, bexc_t, cursor, el_t, sst);

    // rotation: (A=h, Bs=sum, C=scratch) -> after phase: (C, A, Bs)
    for (int ph = 0; ph < 4; ++ph) {
        const bool isInt = (ph % 2 == 0);
        node_pre_kernel<<<NTOT / 256, 256, 0, stream>>>(A, mWin, mbin, C);
        hipMemsetAsync(Bs, 0, HBYTES, stream);
        if (isInt) {
            edge_mlp_kernel3<<<NSLOT_I / EBLK, EBLK, 0, stream>>>(
                ni_int, bi_int, E_INT, el_i, ssi, C,
                mWhid, mbhid, mWout, mbout, Bs);
            gru_kernel4<<<NTOT * 4 / 256, 256, 0, stream>>>(
                A, Bs, deg_i, giWx, giWh, gibi, gibr, C);
        } else {
            edge_mlp_kernel3<<<NSLOT_T / EBLK, EBLK, 0, stream>>>(
                ni_tmp, bi_tmp, E_TMP, el_t, sst, C,
                mWhid, mbhid, mWout, mbout, Bs);
            gru_kernel4<<<NTOT * 4 / 256, 256, 0, stream>>>(
                A, Bs, deg_t, gtWx, gtWh, gtbi, gtbr, C);
        }
        float* oldA = A;  A = C;  C = Bs;  Bs = oldA;
    }

    readout_kernel<<<500, 64, 0, stream>>>(
        A, roWin, robin, roWhid, robhid, roWout, robout, out);
}

// Round 10
// 4884.609 us; speedup vs baseline: 4.9249x; 4.9249x over previous
//
#include <hip/hip_runtime.h>
#include <math.h>

// MPNN on MI355X. R10: GRU rebuilt to satisfy BOTH scalar-GEMV conditions
// learned in R8/R9: (a) weight addresses wave-uniform (R9 violated: ch=gid&3
// made them per-lane divergent -> no s_load scalarization, VALUBusy 3.9%,
// 24ms) and (b) per-pass weight slice <=16KB scalar cache (R8 violated:
// 48KB chunks -> thrash, 1ms). Now: thread-per-node + wave-uniform ch loop
// over 32-col chunks; gate-sequential passes, each slice = 128x32x4B = 16KB.

#define DDIM 128
#define NTOT 128000
#define HBYTES 65536000ULL   // 128000*128*4
#define EBLK 128

__device__ __forceinline__ float gelu_exact(float x) {
    return 0.5f * x * (1.0f + erff(x * 0.70710678118654752440f));
}
__device__ __forceinline__ float sigmoidf_(float x) {
    return 1.0f / (1.0f + expf(-x));
}

__global__ __launch_bounds__(256) void embed_kernel(
    const int* __restrict__ inp, const float* __restrict__ table,
    float* __restrict__ h)
{
    int gid = blockIdx.x * 256 + threadIdx.x;
    if (gid >= NTOT * 32) return;
    int row = gid >> 5;
    int q   = gid & 31;
    int b   = row / 4000;
    int n   = (row % 4000) % 1000;
    int e   = inp[b * 1000 + n];
    ((float4*)h)[gid] = ((const float4*)table)[e * 32 + q];
}

__global__ __launch_bounds__(256) void hist_kernel(
    const int* __restrict__ ni, const int* __restrict__ bi, int E,
    int* __restrict__ deg)
{
    int g = blockIdx.x * 256 + threadIdx.x;
    if (g < E)          atomicAdd(&deg[bi[g]], 1);
    else if (g < 2 * E) atomicAdd(&deg[ni[g - E]], 1);
}

__global__ __launch_bounds__(256) void blockscan_kernel(
    const int* __restrict__ deg, int* __restrict__ offp, int* __restrict__ bsum)
{
    __shared__ int s[256];
    int tid = threadIdx.x;
    int i = blockIdx.x * 256 + tid;
    int v = deg[i];
    s[tid] = v;
    __syncthreads();
    for (int off = 1; off < 256; off <<= 1) {
        int t = (tid >= off) ? s[tid - off] : 0;
        __syncthreads();
        s[tid] += t;
        __syncthreads();
    }
    offp[i] = s[tid] - v;
    if (tid == 255) bsum[blockIdx.x] = s[255];
}

__global__ __launch_bounds__(512) void bscan_kernel(
    const int* __restrict__ bsum, int* __restrict__ bexc, int nb)
{
    __shared__ int s[512];
    int t = threadIdx.x;
    int v = (t < nb) ? bsum[t] : 0;
    s[t] = v;
    __syncthreads();
    for (int off = 1; off < 512; off <<= 1) {
        int u = (t >= off) ? s[t - off] : 0;
        __syncthreads();
        s[t] += u;
        __syncthreads();
    }
    if (t < nb) bexc[t] = s[t] - v;
}

__global__ __launch_bounds__(256) void fill_kernel(
    const int* __restrict__ ni, const int* __restrict__ bi, int E,
    const int* __restrict__ offp, const int* __restrict__ bexc,
    int* __restrict__ cursor, int* __restrict__ elist, int* __restrict__ slotseg)
{
    int g = blockIdx.x * 256 + threadIdx.x;
    if (g >= 2 * E) return;
    int seg = (g < E) ? bi[g] : ni[g - E];
    int pos = atomicAdd(&cursor[seg], 1);
    int slot = offp[seg] + bexc[seg >> 8] + pos;
    elist[slot] = g;
    slotseg[slot] = seg;
}

// Per-node stage-1 factorization: p[v][0:64) = Wtop@h[v] + bin,
// p[v][64:128) = Wbot@h[v]. 16KB wave-uniform weight slices.
__global__ __launch_bounds__(256) void node_pre_kernel(
    const float* __restrict__ h, const float* __restrict__ Win,
    const float* __restrict__ bin, float* __restrict__ p)
{
    const int node = blockIdx.x * 256 + threadIdx.x;
    const float4* h4 = (const float4*)(h + (size_t)node * DDIM);
    float* prow = p + (size_t)node * DDIM;

    for (int c = 0; c < 4; ++c) {
        const int top   = (c < 2) ? 1 : 0;
        const int j0    = (c & 1) * 32;
        const int kbase = top ? 0 : 128;
        float acc[32];
        #pragma unroll
        for (int j = 0; j < 32; ++j) acc[j] = top ? bin[j0 + j] : 0.0f;
        for (int k4 = 0; k4 < 32; ++k4) {
            float4 hv = h4[k4];
            #pragma unroll
            for (int kk = 0; kk < 4; ++kk) {
                const float hk = (&hv.x)[kk];
                const float* wr = Win + (size_t)(kbase + k4 * 4 + kk) * 64 + j0;
                #pragma unroll
                for (int j = 0; j < 32; ++j) acc[j] = fmaf(hk, wr[j], acc[j]);
            }
        }
        float* dst = prow + (top ? 0 : 64) + j0;
        #pragma unroll
        for (int q = 0; q < 8; ++q)
            ((float4*)dst)[q] = make_float4(acc[q*4], acc[q*4+1],
                                            acc[q*4+2], acc[q*4+3]);
    }
}

// Edge MLP from precomputed p, CSR-sorted slots + fused segmented reduction.
__global__ __launch_bounds__(EBLK) void edge_mlp_kernel3(
    const int* __restrict__ ni, const int* __restrict__ bi, int E,
    const int* __restrict__ elist, const int* __restrict__ slotseg,
    const float* __restrict__ p,
    const float* __restrict__ Whid, const float* __restrict__ bhid,
    const float* __restrict__ Wout, const float* __restrict__ bout,
    float* __restrict__ sbuf)
{
    __shared__ float xs[EBLK * 65];
    __shared__ float scat[16 * 68];
    __shared__ int   segLDS[EBLK];
    __shared__ int   segedge[2];
    const int tid  = threadIdx.x;
    const int lane = tid & 63;
    const int s0   = blockIdx.x * EBLK;
    const int slot = s0 + tid;

    const int seg = slotseg[slot];
    const int g   = (seg >= 0) ? elist[slot] : 0;
    int first = 0, second = 0;
    if (seg >= 0) {
        if (g < E) { first = ni[g];     second = bi[g];     }
        else       { first = bi[g - E]; second = ni[g - E]; }
    }
    segLDS[tid] = seg;
    if (tid == 0) segedge[0] = slotseg[s0 - 1];
    if (tid == 1) segedge[1] = slotseg[s0 + EBLK];

    {
        const float4* pa = (const float4*)(p + (size_t)first  * DDIM);
        const float4* pb = (const float4*)(p + (size_t)second * DDIM + 64);
        #pragma unroll 4
        for (int q = 0; q < 16; ++q) {
            float4 a = pa[q], b = pb[q];
            xs[tid * 65 + q * 4 + 0] = gelu_exact(a.x + b.x);
            xs[tid * 65 + q * 4 + 1] = gelu_exact(a.y + b.y);
            xs[tid * 65 + q * 4 + 2] = gelu_exact(a.z + b.z);
            xs[tid * 65 + q * 4 + 3] = gelu_exact(a.w + b.w);
        }
    }

    for (int L = 0; L < 3; ++L) {
        float acc[64];
        #pragma unroll
        for (int j = 0; j < 64; ++j) acc[j] = bhid[L * 64 + j];
        #pragma unroll 4
        for (int k = 0; k < 64; ++k) {
            const float xk = xs[tid * 65 + k];
            const float* wr = Whid + (size_t)L * 4096 + (size_t)k * 64;
            #pragma unroll
            for (int j = 0; j < 64; ++j) acc[j] = fmaf(xk, wr[j], acc[j]);
        }
        #pragma unroll
        for (int j = 0; j < 64; ++j) xs[tid * 65 + j] = gelu_exact(acc[j]);
    }

    for (int half = 0; half < 2; ++half) {
        float acc[64];
        #pragma unroll
        for (int j = 0; j < 64; ++j) acc[j] = bout[half * 64 + j];
        #pragma unroll 4
        for (int k = 0; k < 64; ++k) {
            const float xk = xs[tid * 65 + k];
            const float* wr = Wout + (size_t)k * 128 + half * 64;
            #pragma unroll
            for (int j = 0; j < 64; ++j) acc[j] = fmaf(xk, wr[j], acc[j]);
        }

        int   runSeg = -2;
        float runacc = 0.0f;
        bool  leftC  = true;
        for (int b = 0; b < 8; ++b) {
            __syncthreads();
            if ((tid >> 4) == b) {
                float4* dp = (float4*)&scat[(tid & 15) * 68];
                #pragma unroll
                for (int q = 0; q < 16; ++q)
                    dp[q] = make_float4(acc[q*4], acc[q*4+1], acc[q*4+2], acc[q*4+3]);
            }
            __syncthreads();
            if (tid < 64) {
                for (int r = 0; r < 16; ++r) {
                    const int rowi = b * 16 + r;
                    const int sg = segLDS[rowi];
                    const float v = scat[r * 68 + lane];
                    if (sg != runSeg) {
                        if (runSeg >= 0) {
                            float* pp = sbuf + (size_t)runSeg * DDIM + half * 64 + lane;
                            if (leftC) *pp = runacc;
                            else       atomicAdd(pp, runacc);
                        }
                        runSeg = sg;
                        runacc = v;
                        leftC  = (rowi == 0) ? (segedge[0] != sg) : true;
                    } else {
                        runacc += v;
                    }
                }
            }
        }
        if (tid < 64 && runSeg >= 0) {
            const bool rightC = (segedge[1] != runSeg);
            float* pp = sbuf + (size_t)runSeg * DDIM + half * 64 + lane;
            if (leftC && rightC) *pp = runacc;
            else                 atomicAdd(pp, runacc);
        }
        __syncthreads();
    }
}

// GRU pass: ACC[32] += (row * SCALE) @ W[:, CB..CB+32); W row stride 384.
// CB is wave-uniform -> weights scalarize; slice = 128x32x4B = 16KB.
#define GPASS(ACC, R4, W, CB, SCALE)                                           \
    _Pragma("unroll 2")                                                        \
    for (int k4 = 0; k4 < 32; ++k4) {                                          \
        float4 v_ = (R4)[k4];                                                  \
        _Pragma("unroll")                                                      \
        for (int kk = 0; kk < 4; ++kk) {                                       \
            const float xk_ = (&v_.x)[kk] * (SCALE);                           \
            const float* wr_ = (W) + (size_t)(k4 * 4 + kk) * 384 + (CB);       \
            _Pragma("unroll")                                                  \
            for (int j = 0; j < 32; ++j) ACC[j] = fmaf(xk_, wr_[j], ACC[j]);   \
        }                                                                      \
    }

// GRU (keras reset_after): thread-per-node; wave-uniform ch loop over four
// 32-col chunks; gate-sequential passes (r -> hh -> cand -> z).
__global__ __launch_bounds__(256) void gru_kernel5(
    const float* __restrict__ h, const float* __restrict__ msum,
    const int* __restrict__ deg,
    const float* __restrict__ Wx, const float* __restrict__ Wh,
    const float* __restrict__ bi, const float* __restrict__ br,
    float* __restrict__ hout)
{
    const int node = blockIdx.x * 256 + threadIdx.x;   // grid 500 exact
    const int dg   = deg[node];
    const float cinv = (dg > 0) ? (1.0f / (float)dg) : 0.0f;
    const float4* m4 = (const float4*)(msum + (size_t)node * DDIM);
    const float4* h4 = (const float4*)(h    + (size_t)node * DDIM);
    float* orow = hout + (size_t)node * DDIM;

    for (int ch = 0; ch < 4; ++ch) {                   // wave-uniform
        const int j0 = ch * 32;
        // r_pre
        float rv[32];
        #pragma unroll
        for (int j = 0; j < 32; ++j) rv[j] = bi[128 + j0 + j] + br[128 + j0 + j];
        GPASS(rv, m4, Wx, 128 + j0, cinv)
        GPASS(rv, h4, Wh, 128 + j0, 1.0f)
        // hh
        float hh[32];
        #pragma unroll
        for (int j = 0; j < 32; ++j) hh[j] = br[256 + j0 + j];
        GPASS(hh, h4, Wh, 256 + j0, 1.0f)
        // cand = tanh(xh + sigmoid(r)*hh)
        #pragma unroll
        for (int j = 0; j < 32; ++j)
            rv[j] = sigmoidf_(rv[j]) * hh[j] + bi[256 + j0 + j];
        GPASS(rv, m4, Wx, 256 + j0, cinv)
        #pragma unroll
        for (int j = 0; j < 32; ++j) rv[j] = tanhf(rv[j]);
        // z_pre
        #pragma unroll
        for (int j = 0; j < 32; ++j) hh[j] = bi[j0 + j] + br[j0 + j];
        GPASS(hh, m4, Wx, j0, cinv)
        GPASS(hh, h4, Wh, j0, 1.0f)
        // blend + write this chunk (hout is a third buffer -> no hazard)
        #pragma unroll
        for (int q = 0; q < 8; ++q) {
            float4 hc = h4[ch * 8 + q];
            float4 o;
            #pragma unroll
            for (int kk = 0; kk < 4; ++kk) {
                int j = q * 4 + kk;
                float z = sigmoidf_(hh[j]);
                (&o.x)[kk] = z * (&hc.x)[kk] + (1.0f - z) * rv[j];
            }
            ((float4*)orow)[ch * 8 + q] = o;
        }
    }
}

// Readout: block=64, activations in LDS slice, weights direct from global.
__global__ __launch_bounds__(64) void readout_kernel(
    const float* __restrict__ h,
    const float* __restrict__ Win,  const float* __restrict__ bin,
    const float* __restrict__ Whid, const float* __restrict__ bhid,
    const float* __restrict__ Wout, const float* __restrict__ bout,
    float* __restrict__ out)
{
    __shared__ float xs[64 * 65];
    const int tid = threadIdx.x;
    const int row = blockIdx.x * 64 + tid;
    const int b = row / 1000, n = row % 1000;
    const float4* xrow = (const float4*)(h + ((size_t)b * 4000 + n) * DDIM);

    {
        float acc[64];
        #pragma unroll
        for (int j = 0; j < 64; ++j) acc[j] = bin[j];
        #pragma unroll 2
        for (int k4 = 0; k4 < 32; ++k4) {
            float4 xv = xrow[k4];
            #pragma unroll
            for (int kk = 0; kk < 4; ++kk) {
                const float xk = (&xv.x)[kk];
                const float* wr = Win + (size_t)(k4 * 4 + kk) * 64;
                #pragma unroll
                for (int j = 0; j < 64; ++j) acc[j] = fmaf(xk, wr[j], acc[j]);
            }
        }
        #pragma unroll
        for (int j = 0; j < 64; ++j) xs[tid * 65 + j] = gelu_exact(acc[j]);
    }

    for (int L = 0; L < 3; ++L) {
        float acc[64];
        #pragma unroll
        for (int j = 0; j < 64; ++j) acc[j] = bhid[L * 64 + j];
        #pragma unroll 4
        for (int k = 0; k < 64; ++k) {
            const float xk = xs[tid * 65 + k];
            const float* wr = Whid + (size_t)L * 4096 + (size_t)k * 64;
            #pragma unroll
            for (int j = 0; j < 64; ++j) acc[j] = fmaf(xk, wr[j], acc[j]);
        }
        #pragma unroll
        for (int j = 0; j < 64; ++j) xs[tid * 65 + j] = gelu_exact(acc[j]);
    }

    float acc[10];
    #pragma unroll
    for (int pj = 0; pj < 10; ++pj) acc[pj] = bout[pj];
    #pragma unroll 4
    for (int k = 0; k < 64; ++k) {
        const float xk = xs[tid * 65 + k];
        const float* wr = Wout + k * 10;
        #pragma unroll
        for (int pj = 0; pj < 10; ++pj) acc[pj] = fmaf(xk, wr[pj], acc[pj]);
    }
    #pragma unroll
    for (int pj = 0; pj < 10; ++pj) out[(size_t)row * 10 + pj] = acc[pj];
}

extern "C" void kernel_launch(void* const* d_in, const int* in_sizes, int n_in,
                              void* d_out, int out_size, void* d_ws, size_t ws_size,
                              hipStream_t stream) {
    const int*   node_inputs = (const int*)d_in[0];
    const int*   ni_int = (const int*)d_in[1];
    const int*   bi_int = (const int*)d_in[2];
    const int*   ni_tmp = (const int*)d_in[3];
    const int*   bi_tmp = (const int*)d_in[4];
    const float* embed  = (const float*)d_in[5];
    const float* mWin   = (const float*)d_in[6];
    const float* mbin   = (const float*)d_in[7];
    const float* mWhid  = (const float*)d_in[8];
    const float* mbhid  = (const float*)d_in[9];
    const float* mWout  = (const float*)d_in[10];
    const float* mbout  = (const float*)d_in[11];
    const float* roWin  = (const float*)d_in[12];
    const float* robin  = (const float*)d_in[13];
    const float* roWhid = (const float*)d_in[14];
    const float* robhid = (const float*)d_in[15];
    const float* roWout = (const float*)d_in[16];
    const float* robout = (const float*)d_in[17];
    const float* giWx = (const float*)d_in[18];
    const float* giWh = (const float*)d_in[19];
    const float* gibi = (const float*)d_in[20];
    const float* gibr = (const float*)d_in[21];
    const float* gtWx = (const float*)d_in[22];
    const float* gtWh = (const float*)d_in[23];
    const float* gtbi = (const float*)d_in[24];
    const float* gtbr = (const float*)d_in[25];
    float* out = (float*)d_out;

    const int E_INT = 200000, E_TMP = 96000;
    const int NSLOT_I = 400000;   // 3125*128 exact
    const int NSLOT_T = 192000;   // 1500*128 exact

    char* ws = (char*)d_ws;
    float* A  = (float*)(ws);                 // h
    float* Bs = (float*)(ws + HBYTES);        // segment sums
    float* C  = (float*)(ws + 2 * HBYTES);    // scratch: p, then h'
    char*  ib = ws + 3 * HBYTES;

    int* deg_i   = (int*)(ib);
    int* deg_t   = (int*)(ib + 512000);
    int* offp_i  = (int*)(ib + 1024000);
    int* offp_t  = (int*)(ib + 1536000);
    int* bexc_i  = (int*)(ib + 2048000);
    int* bexc_t  = (int*)(ib + 2052096);
    int* bsum    = (int*)(ib + 2056192);
    int* cursor  = (int*)(ib + 2060288);
    int* el_i    = (int*)(ib + 2572288);
    int* el_t    = (int*)(ib + 4172288);
    int* ssi_raw = (int*)(ib + 4940288);
    int* sst_raw = (int*)(ib + 6540296);
    int* ssi = ssi_raw + 1;
    int* sst = sst_raw + 1;

    embed_kernel<<<16000, 256, 0, stream>>>(node_inputs, embed, A);

    hipMemsetAsync(deg_i, 0, NTOT * sizeof(int), stream);
    hipMemsetAsync(deg_t, 0, NTOT * sizeof(int), stream);
    hist_kernel<<<(2 * E_INT + 255) / 256, 256, 0, stream>>>(ni_int, bi_int, E_INT, deg_i);
    hist_kernel<<<(2 * E_TMP + 255) / 256, 256, 0, stream>>>(ni_tmp, bi_tmp, E_TMP, deg_t);

    hipMemsetAsync(ssi_raw, 0xFF, (size_t)(NSLOT_I + 2) * sizeof(int), stream);
    hipMemsetAsync(sst_raw, 0xFF, (size_t)(NSLOT_T + 2) * sizeof(int), stream);

    blockscan_kernel<<<500, 256, 0, stream>>>(deg_i, offp_i, bsum);
    bscan_kernel<<<1, 512, 0, stream>>>(bsum, bexc_i, 500);
    hipMemsetAsync(cursor, 0, NTOT * sizeof(int), stream);
    fill_kernel<<<(2 * E_INT + 255) / 256, 256, 0, stream>>>(
        ni_int, bi_int, E_INT, offp_i, bexc_i, cursor, el_i, ssi);

    blockscan_kernel<<<500, 256, 0, stream>>>(deg_t, offp_t, bsum);
    bscan_kernel<<<1, 512, 0, stream>>>(bsum, bexc_t, 500);
    hipMemsetAsync(cursor, 0, NTOT * sizeof(int), stream);
    fill_kernel<<<(2 * E_TMP + 255) / 256, 256, 0, stream>>>(
        ni_tmp, bi_tmp, E_TMP, offp_t, bexc_t, cursor, el_t, sst);

    // rotation: (A=h, Bs=sum, C=scratch) -> after phase: (C, A, Bs)
    for (int ph = 0; ph < 4; ++ph) {
        const bool isInt = (ph % 2 == 0);
        node_pre_kernel<<<NTOT / 256, 256, 0, stream>>>(A, mWin, mbin, C);
        hipMemsetAsync(Bs, 0, HBYTES, stream);
        if (isInt) {
            edge_mlp_kernel3<<<NSLOT_I / EBLK, EBLK, 0, stream>>>(
                ni_int, bi_int, E_INT, el_i, ssi, C,
                mWhid, mbhid, mWout, mbout, Bs);
            gru_kernel5<<<NTOT / 256, 256, 0, stream>>>(
                A, Bs, deg_i, giWx, giWh, gibi, gibr, C);
        } else {
            edge_mlp_kernel3<<<NSLOT_T / EBLK, EBLK, 0, stream>>>(
                ni_tmp, bi_tmp, E_TMP, el_t, sst, C,
                mWhid, mbhid, mWout, mbout, Bs);
            gru_kernel5<<<NTOT / 256, 256, 0, stream>>>(
                A, Bs, deg_t, gtWx, gtWh, gtbi, gtbr, C);
        }
        float* oldA = A;  A = C;  C = Bs;  Bs = oldA;
    }

    readout_kernel<<<500, 64, 0, stream>>>(
        A, roWin, robin, roWhid, robhid, roWout, robout, out);
}